// Round 12
// baseline (182.452 us; speedup 1.0000x reference)
//
#include <hip/hip_runtime.h>
#include <stdint.h>

typedef unsigned short u16;
typedef short bf16x8 __attribute__((ext_vector_type(8)));
typedef short bf16x4 __attribute__((ext_vector_type(4)));
typedef float f32x4 __attribute__((ext_vector_type(4)));

#define NN 384
#define DIMC 128
#define NPOS (NN*NN)
#define EPSV 1e-5f
#define LNS 136   // xn LDS row stride in u16

__device__ __forceinline__ u16 f2b(float f){
  union { float f; uint32_t u; } v; v.f = f;
  return (u16)((v.u + 0x7FFFu + ((v.u >> 16) & 1u)) >> 16);
}
__device__ __forceinline__ float b2f(u16 h){
  union { uint32_t u; float f; } v; v.u = ((uint32_t)h) << 16;
  return v.f;
}
__device__ __forceinline__ float sigm(float z){
  return __builtin_amdgcn_rcpf(1.0f + __expf(-z));
}

__device__ __forceinline__ void glds16(const u16* g, u16* l){
  __builtin_amdgcn_global_load_lds((const __attribute__((address_space(1))) void*)(g),
                                   (__attribute__((address_space(3))) void*)(l), 16, 0, 0);
}

// ---------------- kernel 0: fp32 -> bf16 weight conversion ----------------
__global__ void wconv_k(const float* __restrict__ s0, const float* __restrict__ s1,
                        const float* __restrict__ s2, const float* __restrict__ s3,
                        const float* __restrict__ s4, const float* __restrict__ s5,
                        u16* __restrict__ dst){
  int bid = blockIdx.x;
  int m = bid >> 6;
  int off = ((bid & 63) << 8) + threadIdx.x;
  const float* src = s0;
  if (m==1) src=s1; else if (m==2) src=s2; else if (m==3) src=s3;
  else if (m==4) src=s4; else if (m==5) src=s5;
  dst[(m<<14) + off] = f2b(src[off]);
}

// ---------------- kernel 1: LN + 5 projections ----------------
// block: fixed second-index c (j), 64 first-index rows r0..r0+63 (i), 4 waves.
// Weight fragments HOISTED into registers per pass (16-deep load ILP vs serial L2 chains).
// L/R passes: mfma(A=w, B=xn) -> D[e][p]; direct coalesced stores -> [e][j][k=i].
// O pass: mfma(A=w, B=xn) -> D[e][p]; LDS-transpose (reusing xn) -> gate[i][j][e].
__global__ __launch_bounds__(256) void proj_k(
    const float* __restrict__ x, const float* __restrict__ nw, const float* __restrict__ nb,
    const u16* __restrict__ wb,
    const float* __restrict__ left_b, const float* __restrict__ lgate_b,
    const float* __restrict__ right_b, const float* __restrict__ rgate_b,
    const float* __restrict__ ogate_b,
    u16* __restrict__ Lp, u16* __restrict__ Rp, u16* __restrict__ gate)
{
  __shared__ u16 xn[64*LNS];     // 17408 B (reused as transpose buffer in O pass)
  const int tid = threadIdx.x, lane = tid & 63, wid = tid >> 6;
  const int bid = blockIdx.x;
  const int c = bid % NN, r0 = (bid / NN) * 64;
  const int l15 = lane & 15, lg = lane >> 4;

  // ---- LN: 16 lanes per position, 8 ch each ----
  {
    float4 w0 = *(const float4*)(nw + l15*8);
    float4 w1 = *(const float4*)(nw + l15*8 + 4);
    float4 bb0 = *(const float4*)(nb + l15*8);
    float4 bb1 = *(const float4*)(nb + l15*8 + 4);
    float4 v0[4], v1[4];
    #pragma unroll
    for (int it = 0; it < 4; ++it){
      int p = wid*16 + it*4 + lg;
      const float* xp = x + ((size_t)(r0 + p)*NN + c)*DIMC + l15*8;
      v0[it] = *(const float4*)xp;
      v1[it] = *(const float4*)(xp + 4);
    }
    #pragma unroll
    for (int it = 0; it < 4; ++it){
      int p = wid*16 + it*4 + lg;
      float s  = (v0[it].x+v0[it].y)+(v0[it].z+v0[it].w)+((v1[it].x+v1[it].y)+(v1[it].z+v1[it].w));
      float sq = v0[it].x*v0[it].x+v0[it].y*v0[it].y+v0[it].z*v0[it].z+v0[it].w*v0[it].w
               + v1[it].x*v1[it].x+v1[it].y*v1[it].y+v1[it].z*v1[it].z+v1[it].w*v1[it].w;
      #pragma unroll
      for (int o = 8; o; o >>= 1){ s += __shfl_xor(s, o); sq += __shfl_xor(sq, o); }
      float mean = s * (1.0f/128.0f);
      float var  = sq * (1.0f/128.0f) - mean*mean;
      float inv  = rsqrtf(var + EPSV);
      bf16x8 o8;
      o8[0] = (short)f2b((v0[it].x - mean)*inv*w0.x + bb0.x);
      o8[1] = (short)f2b((v0[it].y - mean)*inv*w0.y + bb0.y);
      o8[2] = (short)f2b((v0[it].z - mean)*inv*w0.z + bb0.z);
      o8[3] = (short)f2b((v0[it].w - mean)*inv*w0.w + bb0.w);
      o8[4] = (short)f2b((v1[it].x - mean)*inv*w1.x + bb1.x);
      o8[5] = (short)f2b((v1[it].y - mean)*inv*w1.y + bb1.y);
      o8[6] = (short)f2b((v1[it].z - mean)*inv*w1.z + bb1.z);
      o8[7] = (short)f2b((v1[it].w - mean)*inv*w1.w + bb1.w);
      *(bf16x8*)(xn + p*LNS + l15*8) = o8;
    }
  }
  __syncthreads();

  const int kofs = lg * 8;
  const int wrow = (wid*32 + l15) * 128;
  const int xrowbase = l15 * LNS;

  // ---- passes 0/1: value*sigmoid(gate) -> Lp / Rp ----
  #pragma unroll
  for (int pr = 0; pr < 2; ++pr){
    const u16* wV = wb + (pr*2 + 0)*16384;
    const u16* wG = wb + (pr*2 + 1)*16384;
    const float* bV = pr ? right_b : left_b;
    const float* bG = pr ? rgate_b : lgate_b;
    u16* dst = pr ? Rp : Lp;

    // hoist all 16 weight fragments of this pass (compile-time indices only)
    bf16x8 wvr[4][2], wgr[4][2];
    #pragma unroll
    for (int ks = 0; ks < 4; ++ks)
      #pragma unroll
      for (int n = 0; n < 2; ++n){
        wvr[ks][n] = *(const bf16x8*)(wV + wrow + n*16*128 + ks*32 + kofs);
        wgr[ks][n] = *(const bf16x8*)(wG + wrow + n*16*128 + ks*32 + kofs);
      }

    f32x4 aV[2][4], aG[2][4];
    #pragma unroll
    for (int n = 0; n < 2; ++n)
      #pragma unroll
      for (int pt = 0; pt < 4; ++pt){ aV[n][pt] = {0.f,0.f,0.f,0.f}; aG[n][pt] = {0.f,0.f,0.f,0.f}; }

    #pragma unroll
    for (int ks = 0; ks < 4; ++ks){
      bf16x8 xf[4];
      #pragma unroll
      for (int pt = 0; pt < 4; ++pt)
        xf[pt] = *(const bf16x8*)(xn + xrowbase + pt*16*LNS + ks*32 + kofs);
      #pragma unroll
      for (int n = 0; n < 2; ++n){
        #pragma unroll
        for (int pt = 0; pt < 4; ++pt){
          aV[n][pt] = __builtin_amdgcn_mfma_f32_16x16x32_bf16(wvr[ks][n], xf[pt], aV[n][pt], 0, 0, 0);
          aG[n][pt] = __builtin_amdgcn_mfma_f32_16x16x32_bf16(wgr[ks][n], xf[pt], aG[n][pt], 0, 0, 0);
        }
      }
    }
    #pragma unroll
    for (int n = 0; n < 2; ++n){
      int ebase = wid*32 + n*16 + lg*4;
      float4 bv4 = *(const float4*)(bV + ebase);
      float4 bg4 = *(const float4*)(bG + ebase);
      #pragma unroll
      for (int r = 0; r < 4; ++r){
        float bv = r==0?bv4.x : r==1?bv4.y : r==2?bv4.z : bv4.w;
        float bg = r==0?bg4.x : r==1?bg4.y : r==2?bg4.z : bg4.w;
        u16* base = dst + (size_t)(ebase + r)*NPOS + (size_t)c*NN + r0 + l15;
        #pragma unroll
        for (int pt = 0; pt < 4; ++pt){
          float v = (aV[n][pt][r] + bv) * sigm(aG[n][pt][r] + bg);
          base[pt*16] = f2b(v);
        }
      }
    }
  }

  // ---- pass 2: ogate -> sigmoid -> gate[i][j][e] via LDS transpose (reuse xn) ----
  {
    const u16* wO = wb + 4*16384;
    bf16x8 wor[4][2];
    #pragma unroll
    for (int ks = 0; ks < 4; ++ks)
      #pragma unroll
      for (int n = 0; n < 2; ++n)
        wor[ks][n] = *(const bf16x8*)(wO + wrow + n*16*128 + ks*32 + kofs);

    f32x4 aO[2][4];
    #pragma unroll
    for (int n = 0; n < 2; ++n)
      #pragma unroll
      for (int pt = 0; pt < 4; ++pt) aO[n][pt] = {0.f,0.f,0.f,0.f};

    #pragma unroll
    for (int ks = 0; ks < 4; ++ks){
      bf16x8 xf[4];
      #pragma unroll
      for (int pt = 0; pt < 4; ++pt)
        xf[pt] = *(const bf16x8*)(xn + xrowbase + pt*16*LNS + ks*32 + kofs);
      #pragma unroll
      for (int n = 0; n < 2; ++n){
        #pragma unroll
        for (int pt = 0; pt < 4; ++pt)
          aO[n][pt] = __builtin_amdgcn_mfma_f32_16x16x32_bf16(wor[ks][n], xf[pt], aO[n][pt], 0, 0, 0);
      }
    }
    __syncthreads();   // all waves done reading xn -> safe to overwrite
    #pragma unroll
    for (int n = 0; n < 2; ++n){
      int ebase = wid*32 + n*16 + lg*4;
      float4 bo4 = *(const float4*)(ogate_b + ebase);
      #pragma unroll
      for (int r = 0; r < 4; ++r){
        float bo = r==0?bo4.x : r==1?bo4.y : r==2?bo4.z : bo4.w;
        #pragma unroll
        for (int pt = 0; pt < 4; ++pt)
          xn[(pt*16 + l15)*LNS + ebase + r] = f2b(sigm(aO[n][pt][r] + bo));
      }
    }
    __syncthreads();
    #pragma unroll
    for (int it = 0; it < 4; ++it){
      int idx = tid + it*256;
      int p = idx >> 4, s = idx & 15;
      *(bf16x8*)(gate + ((size_t)(r0 + p)*NN + c)*DIMC + s*8) = *(const bf16x8*)(xn + p*LNS + s*8);
    }
  }
}

// ---------------- kernel 2: triangle einsum, BK=64, global_load_lds + XOR swizzle ----------------
// XCD-aware block remap: all 9 tiles of one d stay on one XCD (panel reuse in its L2).
__global__ __launch_bounds__(256) void phase2_k(const u16* __restrict__ Rp, const u16* __restrict__ Lp,
                                                u16* __restrict__ outp){
  __shared__ u16 lds[17408];
  u16* At = lds;
  u16* Bt = lds + 8192;
  const int tid = threadIdx.x, lane = tid & 63, wid = tid >> 6;
  const int bid = blockIdx.x;
  // bijective remap: 1152 = 8 XCDs x 16 d x 9 tiles
  const int xcd = bid & 7, kk = bid >> 3;
  const int d = xcd*16 + kk/9, tile = kk % 9;
  const int i0 = (tile/3)*128, j0 = (tile%3)*128;
  const int wm = wid >> 1, wn = wid & 1;
  const int iw = wm*64, jw = wn*64;
  const int l15 = lane & 15, lg = lane >> 4;
  const int rmask = l15 & 7;

  int srcoff[4];
  #pragma unroll
  for (int cc = 0; cc < 4; ++cc){
    int idx = wid*256 + cc*64 + lane;
    int row = idx >> 3, slot = idx & 7;
    srcoff[cc] = row*NN + ((slot ^ (row & 7)) * 8);
  }

  f32x4 acc[4][4];
  #pragma unroll
  for (int m = 0; m < 4; ++m)
    #pragma unroll
    for (int n = 0; n < 4; ++n) acc[m][n] = {0.f,0.f,0.f,0.f};

  const u16* Rt0 = Rp + (size_t)d*NPOS + (size_t)i0*NN;
  const u16* Lt0 = Lp + (size_t)d*NPOS + (size_t)j0*NN;

  for (int k0 = 0; k0 < NN; k0 += 64){
    __syncthreads();
    #pragma unroll
    for (int cc = 0; cc < 4; ++cc){
      glds16(Rt0 + k0 + srcoff[cc], At + (wid*4 + cc)*512);
      glds16(Lt0 + k0 + srcoff[cc], Bt + (wid*4 + cc)*512);
    }
    asm volatile("s_waitcnt vmcnt(0)" ::: "memory");
    __syncthreads();
    #pragma unroll
    for (int ks = 0; ks < 2; ++ks){
      int sl = ((ks*4 + lg) ^ rmask) * 8;
      bf16x8 af[4], bfr[4];
      #pragma unroll
      for (int m = 0; m < 4; ++m)
        af[m] = *(const bf16x8*)(At + (iw + m*16 + l15)*64 + sl);
      #pragma unroll
      for (int n = 0; n < 4; ++n)
        bfr[n] = *(const bf16x8*)(Bt + (jw + n*16 + l15)*64 + sl);
      #pragma unroll
      for (int m = 0; m < 4; ++m)
        #pragma unroll
        for (int n = 0; n < 4; ++n)
          acc[m][n] = __builtin_amdgcn_mfma_f32_16x16x32_bf16(af[m], bfr[n], acc[m][n], 0, 0, 0);
    }
  }

  __syncthreads();
  #pragma unroll
  for (int m = 0; m < 4; ++m)
    #pragma unroll
    for (int n = 0; n < 4; ++n)
      #pragma unroll
      for (int r = 0; r < 4; ++r)
        lds[(iw + m*16 + lg*4 + r)*136 + jw + n*16 + l15] = f2b(acc[m][n][r]);
  __syncthreads();
  u16* ob = outp + (size_t)d*NPOS;
  #pragma unroll
  for (int it = 0; it < 8; ++it){
    int idx = tid + it*256;
    int i = idx >> 4, s = idx & 15;
    *(bf16x8*)(ob + (size_t)(i0 + i)*NN + j0 + s*8) = *(const bf16x8*)(lds + i*136 + s*8);
  }
}

// ---------------- kernel 3: LN + out-projection + gate ----------------
// block: fixed i, 64 consecutive j. gate layout [i][j][e] -> 32B-run reads.
__global__ __launch_bounds__(256) void phase3_k(const u16* __restrict__ outp,
    const float* __restrict__ tonw, const float* __restrict__ tonb,
    const u16* __restrict__ wOut, const float* __restrict__ out_b,
    const u16* __restrict__ gate, float* __restrict__ out)
{
  __shared__ u16 xn2[64*132];
  __shared__ float reds[4][64], redq[4][64];
  __shared__ float marr[64], iarr[64];
  const int tid = threadIdx.x, lane = tid & 63, wid = tid >> 6;
  const int bid = blockIdx.x;
  const int i = bid % NN, j0 = (bid / NN) * 64;
  const int l15 = lane & 15, lg = lane >> 4;

  float rv[32];
  float s = 0.f, sq = 0.f;
  #pragma unroll
  for (int q = 0; q < 32; ++q){
    int h = wid*32 + q;
    float v = b2f(outp[(size_t)h*NPOS + (size_t)i*NN + j0 + lane]);
    rv[q] = v; s += v; sq += v*v;
  }
  reds[wid][lane] = s; redq[wid][lane] = sq;
  __syncthreads();
  if (tid < 64){
    float ts = reds[0][tid] + reds[1][tid] + reds[2][tid] + reds[3][tid];
    float tq = redq[0][tid] + redq[1][tid] + redq[2][tid] + redq[3][tid];
    float m  = ts * (1.f/128.f);
    float var = tq * (1.f/128.f) - m*m;
    marr[tid] = m; iarr[tid] = rsqrtf(var + EPSV);
  }
  __syncthreads();
  float m = marr[lane], inv = iarr[lane];
  #pragma unroll
  for (int q = 0; q < 32; ++q){
    int h = wid*32 + q;
    float v = (rv[q] - m)*inv*tonw[h] + tonb[h];
    xn2[lane*132 + h] = f2b(v);
  }
  __syncthreads();

  f32x4 acc[8];
  #pragma unroll
  for (int n = 0; n < 8; ++n) acc[n] = {0.f,0.f,0.f,0.f};
  const int row = wid*16 + l15;
  const int kofs = lg * 8;
  #pragma unroll
  for (int ks = 0; ks < 4; ++ks){
    const u16* ap = xn2 + row*132 + ks*32 + kofs;
    bf16x4 a0 = *(const bf16x4*)ap;
    bf16x4 a1 = *(const bf16x4*)(ap + 4);
    bf16x8 af = __builtin_shufflevector(a0, a1, 0,1,2,3,4,5,6,7);
    #pragma unroll
    for (int n = 0; n < 8; ++n){
      bf16x8 bm = *(const bf16x8*)(wOut + (n*16 + l15)*128 + ks*32 + kofs);
      acc[n] = __builtin_amdgcn_mfma_f32_16x16x32_bf16(af, bm, acc[n], 0, 0, 0);
    }
  }
  #pragma unroll
  for (int n = 0; n < 8; ++n){
    int dd = n*16 + l15;
    float bo = out_b[dd];
    #pragma unroll
    for (int r = 0; r < 4; ++r){
      int p = wid*16 + lg*4 + r;
      size_t base = ((size_t)i*NN + j0 + p)*DIMC + dd;
      float g = b2f(gate[base]);
      out[base] = (acc[n][r] + bo) * g;
    }
  }
}

extern "C" void kernel_launch(void* const* d_in, const int* in_sizes, int n_in,
                              void* d_out, int out_size, void* d_ws, size_t ws_size,
                              hipStream_t stream){
  const float* x       = (const float*)d_in[0];
  const float* norm_w  = (const float*)d_in[1];
  const float* norm_b  = (const float*)d_in[2];
  const float* left_w  = (const float*)d_in[3];
  const float* left_b  = (const float*)d_in[4];
  const float* right_w = (const float*)d_in[5];
  const float* right_b = (const float*)d_in[6];
  const float* lgate_w = (const float*)d_in[7];
  const float* lgate_b = (const float*)d_in[8];
  const float* rgate_w = (const float*)d_in[9];
  const float* rgate_b = (const float*)d_in[10];
  const float* ogate_w = (const float*)d_in[11];
  const float* ogate_b = (const float*)d_in[12];
  const float* ton_w   = (const float*)d_in[13];
  const float* ton_b   = (const float*)d_in[14];
  const float* out_w   = (const float*)d_in[15];
  const float* out_b   = (const float*)d_in[16];

  char* ws = (char*)d_ws;
  const size_t SZ = (size_t)NPOS * DIMC * sizeof(u16);
  u16* Lp   = (u16*)(ws);
  u16* Rp   = (u16*)(ws + SZ);
  u16* gate = (u16*)(ws + 2*SZ);
  u16* outp = (u16*)(ws + 3*SZ);
  u16* wb   = (u16*)(ws + 4*SZ);

  wconv_k<<<dim3(384), dim3(256), 0, stream>>>(left_w, lgate_w, right_w, rgate_w, ogate_w, out_w, wb);
  proj_k<<<dim3(2304), dim3(256), 0, stream>>>(x, norm_w, norm_b, wb,
      left_b, lgate_b, right_b, rgate_b, ogate_b, Lp, Rp, gate);
  phase2_k<<<dim3(1152), dim3(256), 0, stream>>>(Rp, Lp, outp);
  phase3_k<<<dim3(2304), dim3(256), 0, stream>>>(outp, ton_w, ton_b, wb + 5*16384, out_b, gate, (float*)d_out);
}

// Round 13
// 169.674 us; speedup vs baseline: 1.0753x; 1.0753x over previous
//
#include <hip/hip_runtime.h>
#include <stdint.h>

typedef unsigned short u16;
typedef short bf16x8 __attribute__((ext_vector_type(8)));
typedef short bf16x4 __attribute__((ext_vector_type(4)));
typedef float f32x4 __attribute__((ext_vector_type(4)));

#define NN 384
#define DIMC 128
#define NPOS (NN*NN)
#define EPSV 1e-5f
#define LNS 136   // xn LDS row stride in u16

__device__ __forceinline__ u16 f2b(float f){
  union { float f; uint32_t u; } v; v.f = f;
  return (u16)((v.u + 0x7FFFu + ((v.u >> 16) & 1u)) >> 16);
}
__device__ __forceinline__ float b2f(u16 h){
  union { uint32_t u; float f; } v; v.u = ((uint32_t)h) << 16;
  return v.f;
}
__device__ __forceinline__ float sigm(float z){
  return __builtin_amdgcn_rcpf(1.0f + __expf(-z));
}

__device__ __forceinline__ void glds16(const u16* g, u16* l){
  __builtin_amdgcn_global_load_lds((const __attribute__((address_space(1))) void*)(g),
                                   (__attribute__((address_space(3))) void*)(l), 16, 0, 0);
}

// ---------------- kernel 0: fp32 -> bf16 weight conversion ----------------
__global__ void wconv_k(const float* __restrict__ s0, const float* __restrict__ s1,
                        const float* __restrict__ s2, const float* __restrict__ s3,
                        const float* __restrict__ s4, const float* __restrict__ s5,
                        u16* __restrict__ dst){
  int bid = blockIdx.x;
  int m = bid >> 6;
  int off = ((bid & 63) << 8) + threadIdx.x;
  const float* src = s0;
  if (m==1) src=s1; else if (m==2) src=s2; else if (m==3) src=s3;
  else if (m==4) src=s4; else if (m==5) src=s5;
  dst[(m<<14) + off] = f2b(src[off]);
}

// ---------------- kernel 1: LN + 5 projections (r11 config) ----------------
// block: fixed second-index c (j), 64 first-index rows r0..r0+63 (i), 4 waves.
// L/R passes: mfma(A=w, B=xn) -> D[e][p]; direct coalesced stores -> [e][j][k=i].
// O pass: mfma(A=w, B=xn) -> D[e][p]; LDS-transpose (reusing xn) -> gate[i][j][e].
__global__ __launch_bounds__(256) void proj_k(
    const float* __restrict__ x, const float* __restrict__ nw, const float* __restrict__ nb,
    const u16* __restrict__ wb,
    const float* __restrict__ left_b, const float* __restrict__ lgate_b,
    const float* __restrict__ right_b, const float* __restrict__ rgate_b,
    const float* __restrict__ ogate_b,
    u16* __restrict__ Lp, u16* __restrict__ Rp, u16* __restrict__ gate)
{
  __shared__ u16 xn[64*LNS];     // 17408 B (reused as transpose buffer in O pass)
  const int tid = threadIdx.x, lane = tid & 63, wid = tid >> 6;
  const int bid = blockIdx.x;
  const int c = bid % NN, r0 = (bid / NN) * 64;
  const int l15 = lane & 15, lg = lane >> 4;

  // ---- LN: 16 lanes per position, 8 ch each ----
  {
    float4 w0 = *(const float4*)(nw + l15*8);
    float4 w1 = *(const float4*)(nw + l15*8 + 4);
    float4 bb0 = *(const float4*)(nb + l15*8);
    float4 bb1 = *(const float4*)(nb + l15*8 + 4);
    float4 v0[4], v1[4];
    #pragma unroll
    for (int it = 0; it < 4; ++it){
      int p = wid*16 + it*4 + lg;
      const float* xp = x + ((size_t)(r0 + p)*NN + c)*DIMC + l15*8;
      v0[it] = *(const float4*)xp;
      v1[it] = *(const float4*)(xp + 4);
    }
    #pragma unroll
    for (int it = 0; it < 4; ++it){
      int p = wid*16 + it*4 + lg;
      float s  = (v0[it].x+v0[it].y)+(v0[it].z+v0[it].w)+((v1[it].x+v1[it].y)+(v1[it].z+v1[it].w));
      float sq = v0[it].x*v0[it].x+v0[it].y*v0[it].y+v0[it].z*v0[it].z+v0[it].w*v0[it].w
               + v1[it].x*v1[it].x+v1[it].y*v1[it].y+v1[it].z*v1[it].z+v1[it].w*v1[it].w;
      #pragma unroll
      for (int o = 8; o; o >>= 1){ s += __shfl_xor(s, o); sq += __shfl_xor(sq, o); }
      float mean = s * (1.0f/128.0f);
      float var  = sq * (1.0f/128.0f) - mean*mean;
      float inv  = rsqrtf(var + EPSV);
      bf16x8 o8;
      o8[0] = (short)f2b((v0[it].x - mean)*inv*w0.x + bb0.x);
      o8[1] = (short)f2b((v0[it].y - mean)*inv*w0.y + bb0.y);
      o8[2] = (short)f2b((v0[it].z - mean)*inv*w0.z + bb0.z);
      o8[3] = (short)f2b((v0[it].w - mean)*inv*w0.w + bb0.w);
      o8[4] = (short)f2b((v1[it].x - mean)*inv*w1.x + bb1.x);
      o8[5] = (short)f2b((v1[it].y - mean)*inv*w1.y + bb1.y);
      o8[6] = (short)f2b((v1[it].z - mean)*inv*w1.z + bb1.z);
      o8[7] = (short)f2b((v1[it].w - mean)*inv*w1.w + bb1.w);
      *(bf16x8*)(xn + p*LNS + l15*8) = o8;
    }
  }
  __syncthreads();

  const int kofs = lg * 8;
  const int wrow = (wid*32 + l15) * 128;
  const int xrowbase = l15 * LNS;

  // ---- passes 0/1: value*sigmoid(gate) -> Lp / Rp ----
  #pragma unroll
  for (int pr = 0; pr < 2; ++pr){
    const u16* wV = wb + (pr*2 + 0)*16384;
    const u16* wG = wb + (pr*2 + 1)*16384;
    const float* bV = pr ? right_b : left_b;
    const float* bG = pr ? rgate_b : lgate_b;
    u16* dst = pr ? Rp : Lp;

    f32x4 aV[2][4], aG[2][4];
    #pragma unroll
    for (int n = 0; n < 2; ++n)
      #pragma unroll
      for (int pt = 0; pt < 4; ++pt){ aV[n][pt] = {0.f,0.f,0.f,0.f}; aG[n][pt] = {0.f,0.f,0.f,0.f}; }

    #pragma unroll
    for (int ks = 0; ks < 4; ++ks){
      bf16x8 xf[4];
      #pragma unroll
      for (int pt = 0; pt < 4; ++pt)
        xf[pt] = *(const bf16x8*)(xn + xrowbase + pt*16*LNS + ks*32 + kofs);
      #pragma unroll
      for (int n = 0; n < 2; ++n){
        bf16x8 wv = *(const bf16x8*)(wV + wrow + n*16*128 + ks*32 + kofs);
        bf16x8 wg = *(const bf16x8*)(wG + wrow + n*16*128 + ks*32 + kofs);
        #pragma unroll
        for (int pt = 0; pt < 4; ++pt){
          aV[n][pt] = __builtin_amdgcn_mfma_f32_16x16x32_bf16(wv, xf[pt], aV[n][pt], 0, 0, 0);
          aG[n][pt] = __builtin_amdgcn_mfma_f32_16x16x32_bf16(wg, xf[pt], aG[n][pt], 0, 0, 0);
        }
      }
    }
    #pragma unroll
    for (int n = 0; n < 2; ++n){
      int ebase = wid*32 + n*16 + lg*4;
      float4 bv4 = *(const float4*)(bV + ebase);
      float4 bg4 = *(const float4*)(bG + ebase);
      #pragma unroll
      for (int r = 0; r < 4; ++r){
        float bv = r==0?bv4.x : r==1?bv4.y : r==2?bv4.z : bv4.w;
        float bg = r==0?bg4.x : r==1?bg4.y : r==2?bg4.z : bg4.w;
        u16* base = dst + (size_t)(ebase + r)*NPOS + (size_t)c*NN + r0 + l15;
        #pragma unroll
        for (int pt = 0; pt < 4; ++pt){
          float v = (aV[n][pt][r] + bv) * sigm(aG[n][pt][r] + bg);
          base[pt*16] = f2b(v);
        }
      }
    }
  }

  // ---- pass 2: ogate -> sigmoid -> gate[i][j][e] via LDS transpose (reuse xn) ----
  {
    const u16* wO = wb + 4*16384;
    f32x4 aO[2][4];
    #pragma unroll
    for (int n = 0; n < 2; ++n)
      #pragma unroll
      for (int pt = 0; pt < 4; ++pt) aO[n][pt] = {0.f,0.f,0.f,0.f};

    #pragma unroll
    for (int ks = 0; ks < 4; ++ks){
      bf16x8 xf[4];
      #pragma unroll
      for (int pt = 0; pt < 4; ++pt)
        xf[pt] = *(const bf16x8*)(xn + xrowbase + pt*16*LNS + ks*32 + kofs);
      #pragma unroll
      for (int n = 0; n < 2; ++n){
        bf16x8 wo = *(const bf16x8*)(wO + wrow + n*16*128 + ks*32 + kofs);
        #pragma unroll
        for (int pt = 0; pt < 4; ++pt)
          aO[n][pt] = __builtin_amdgcn_mfma_f32_16x16x32_bf16(wo, xf[pt], aO[n][pt], 0, 0, 0);
      }
    }
    __syncthreads();   // all waves done reading xn -> safe to overwrite
    #pragma unroll
    for (int n = 0; n < 2; ++n){
      int ebase = wid*32 + n*16 + lg*4;
      float4 bo4 = *(const float4*)(ogate_b + ebase);
      #pragma unroll
      for (int r = 0; r < 4; ++r){
        float bo = r==0?bo4.x : r==1?bo4.y : r==2?bo4.z : bo4.w;
        #pragma unroll
        for (int pt = 0; pt < 4; ++pt)
          xn[(pt*16 + l15)*LNS + ebase + r] = f2b(sigm(aO[n][pt][r] + bo));
      }
    }
    __syncthreads();
    #pragma unroll
    for (int it = 0; it < 4; ++it){
      int idx = tid + it*256;
      int p = idx >> 4, s = idx & 15;
      *(bf16x8*)(gate + ((size_t)(r0 + p)*NN + c)*DIMC + s*8) = *(const bf16x8*)(xn + p*LNS + s*8);
    }
  }
}

// ---------------- kernel 2: triangle einsum, BK=64, global_load_lds + XOR swizzle ----------------
// XCD-aware block remap: all 9 tiles of one d stay on one XCD (panel reuse in its L2).
__global__ __launch_bounds__(256) void phase2_k(const u16* __restrict__ Rp, const u16* __restrict__ Lp,
                                                u16* __restrict__ outp){
  __shared__ u16 lds[17408];
  u16* At = lds;
  u16* Bt = lds + 8192;
  const int tid = threadIdx.x, lane = tid & 63, wid = tid >> 6;
  const int bid = blockIdx.x;
  // bijective remap: 1152 = 8 XCDs x 16 d x 9 tiles
  const int xcd = bid & 7, kk = bid >> 3;
  const int d = xcd*16 + kk/9, tile = kk % 9;
  const int i0 = (tile/3)*128, j0 = (tile%3)*128;
  const int wm = wid >> 1, wn = wid & 1;
  const int iw = wm*64, jw = wn*64;
  const int l15 = lane & 15, lg = lane >> 4;
  const int rmask = l15 & 7;

  int srcoff[4];
  #pragma unroll
  for (int cc = 0; cc < 4; ++cc){
    int idx = wid*256 + cc*64 + lane;
    int row = idx >> 3, slot = idx & 7;
    srcoff[cc] = row*NN + ((slot ^ (row & 7)) * 8);
  }

  f32x4 acc[4][4];
  #pragma unroll
  for (int m = 0; m < 4; ++m)
    #pragma unroll
    for (int n = 0; n < 4; ++n) acc[m][n] = {0.f,0.f,0.f,0.f};

  const u16* Rt0 = Rp + (size_t)d*NPOS + (size_t)i0*NN;
  const u16* Lt0 = Lp + (size_t)d*NPOS + (size_t)j0*NN;

  for (int k0 = 0; k0 < NN; k0 += 64){
    __syncthreads();
    #pragma unroll
    for (int cc = 0; cc < 4; ++cc){
      glds16(Rt0 + k0 + srcoff[cc], At + (wid*4 + cc)*512);
      glds16(Lt0 + k0 + srcoff[cc], Bt + (wid*4 + cc)*512);
    }
    asm volatile("s_waitcnt vmcnt(0)" ::: "memory");
    __syncthreads();
    #pragma unroll
    for (int ks = 0; ks < 2; ++ks){
      int sl = ((ks*4 + lg) ^ rmask) * 8;
      bf16x8 af[4], bfr[4];
      #pragma unroll
      for (int m = 0; m < 4; ++m)
        af[m] = *(const bf16x8*)(At + (iw + m*16 + l15)*64 + sl);
      #pragma unroll
      for (int n = 0; n < 4; ++n)
        bfr[n] = *(const bf16x8*)(Bt + (jw + n*16 + l15)*64 + sl);
      #pragma unroll
      for (int m = 0; m < 4; ++m)
        #pragma unroll
        for (int n = 0; n < 4; ++n)
          acc[m][n] = __builtin_amdgcn_mfma_f32_16x16x32_bf16(af[m], bfr[n], acc[m][n], 0, 0, 0);
    }
  }

  __syncthreads();
  #pragma unroll
  for (int m = 0; m < 4; ++m)
    #pragma unroll
    for (int n = 0; n < 4; ++n)
      #pragma unroll
      for (int r = 0; r < 4; ++r)
        lds[(iw + m*16 + lg*4 + r)*136 + jw + n*16 + l15] = f2b(acc[m][n][r]);
  __syncthreads();
  u16* ob = outp + (size_t)d*NPOS;
  #pragma unroll
  for (int it = 0; it < 8; ++it){
    int idx = tid + it*256;
    int i = idx >> 4, s = idx & 15;
    *(bf16x8*)(ob + (size_t)(i0 + i)*NN + j0 + s*8) = *(const bf16x8*)(lds + i*136 + s*8);
  }
}

// ---------------- kernel 3: LN + out-projection + gate, ZERO LDS / ZERO barriers ----------------
// block: fixed i, 64 consecutive j. Lane (l15,lg) of wave w owns position j = j0+w*16+l15
// and channels h = ks*32 + lg*8 + e -- exactly the MFMA A-fragment layout, loaded directly.
// LN reduce over h: in-lane 32-sum + shfl_xor(16) + shfl_xor(32) across lg-groups (same j).
__global__ __launch_bounds__(256) void phase3_k(const u16* __restrict__ outp,
    const float* __restrict__ tonw, const float* __restrict__ tonb,
    const u16* __restrict__ wOut, const float* __restrict__ out_b,
    const u16* __restrict__ gate, float* __restrict__ out)
{
  const int tid = threadIdx.x, lane = tid & 63, wid = tid >> 6;
  const int bid = blockIdx.x;
  const int i = bid % NN, j0 = (bid / NN) * 64;
  const int l15 = lane & 15, lg = lane >> 4;

  // fragment-order loads + LN statistics
  const u16* ob = outp + (size_t)i*NN + j0 + wid*16 + l15;
  float rv[4][8];
  float s = 0.f, sq = 0.f;
  #pragma unroll
  for (int ks = 0; ks < 4; ++ks){
    #pragma unroll
    for (int e = 0; e < 8; ++e){
      int h = ks*32 + lg*8 + e;
      float v = b2f(ob[(size_t)h*NPOS]);
      rv[ks][e] = v; s += v; sq += v*v;
    }
  }
  s += __shfl_xor(s, 16); sq += __shfl_xor(sq, 16);
  s += __shfl_xor(s, 32); sq += __shfl_xor(sq, 32);
  const float m  = s * (1.f/128.f);
  const float var = sq * (1.f/128.f) - m*m;
  const float inv = rsqrtf(var + EPSV);

  // normalize into A-fragments (bf16)
  bf16x8 af[4];
  #pragma unroll
  for (int ks = 0; ks < 4; ++ks){
    const float* wp = tonw + ks*32 + lg*8;
    const float* bp = tonb + ks*32 + lg*8;
    float4 w0 = *(const float4*)wp;
    float4 w1 = *(const float4*)(wp + 4);
    float4 b0 = *(const float4*)bp;
    float4 b1 = *(const float4*)(bp + 4);
    af[ks][0] = (short)f2b((rv[ks][0] - m)*inv*w0.x + b0.x);
    af[ks][1] = (short)f2b((rv[ks][1] - m)*inv*w0.y + b0.y);
    af[ks][2] = (short)f2b((rv[ks][2] - m)*inv*w0.z + b0.z);
    af[ks][3] = (short)f2b((rv[ks][3] - m)*inv*w0.w + b0.w);
    af[ks][4] = (short)f2b((rv[ks][4] - m)*inv*w1.x + b1.x);
    af[ks][5] = (short)f2b((rv[ks][5] - m)*inv*w1.y + b1.y);
    af[ks][6] = (short)f2b((rv[ks][6] - m)*inv*w1.z + b1.z);
    af[ks][7] = (short)f2b((rv[ks][7] - m)*inv*w1.w + b1.w);
  }

  // out-projection GEMM
  const int kofs = lg * 8;
  f32x4 acc[8];
  #pragma unroll
  for (int n = 0; n < 8; ++n) acc[n] = {0.f,0.f,0.f,0.f};
  #pragma unroll
  for (int ks = 0; ks < 4; ++ks){
    #pragma unroll
    for (int n = 0; n < 8; ++n){
      bf16x8 bm = *(const bf16x8*)(wOut + (n*16 + l15)*128 + ks*32 + kofs);
      acc[n] = __builtin_amdgcn_mfma_f32_16x16x32_bf16(af[ks], bm, acc[n], 0, 0, 0);
    }
  }

  // epilogue: bias + gate (gate[i][j][e], e-contiguous)
  #pragma unroll
  for (int n = 0; n < 8; ++n){
    int dd = n*16 + l15;
    float bo = out_b[dd];
    #pragma unroll
    for (int r = 0; r < 4; ++r){
      int p = wid*16 + lg*4 + r;
      size_t base = ((size_t)i*NN + j0 + p)*DIMC + dd;
      float g = b2f(gate[base]);
      out[base] = (acc[n][r] + bo) * g;
    }
  }
}

extern "C" void kernel_launch(void* const* d_in, const int* in_sizes, int n_in,
                              void* d_out, int out_size, void* d_ws, size_t ws_size,
                              hipStream_t stream){
  const float* x       = (const float*)d_in[0];
  const float* norm_w  = (const float*)d_in[1];
  const float* norm_b  = (const float*)d_in[2];
  const float* left_w  = (const float*)d_in[3];
  const float* left_b  = (const float*)d_in[4];
  const float* right_w = (const float*)d_in[5];
  const float* right_b = (const float*)d_in[6];
  const float* lgate_w = (const float*)d_in[7];
  const float* lgate_b = (const float*)d_in[8];
  const float* rgate_w = (const float*)d_in[9];
  const float* rgate_b = (const float*)d_in[10];
  const float* ogate_w = (const float*)d_in[11];
  const float* ogate_b = (const float*)d_in[12];
  const float* ton_w   = (const float*)d_in[13];
  const float* ton_b   = (const float*)d_in[14];
  const float* out_w   = (const float*)d_in[15];
  const float* out_b   = (const float*)d_in[16];

  char* ws = (char*)d_ws;
  const size_t SZ = (size_t)NPOS * DIMC * sizeof(u16);
  u16* Lp   = (u16*)(ws);
  u16* Rp   = (u16*)(ws + SZ);
  u16* gate = (u16*)(ws + 2*SZ);
  u16* outp = (u16*)(ws + 3*SZ);
  u16* wb   = (u16*)(ws + 4*SZ);

  wconv_k<<<dim3(384), dim3(256), 0, stream>>>(left_w, lgate_w, right_w, rgate_w, ogate_w, out_w, wb);
  proj_k<<<dim3(2304), dim3(256), 0, stream>>>(x, norm_w, norm_b, wb,
      left_b, lgate_b, right_b, rgate_b, ogate_b, Lp, Rp, gate);
  phase2_k<<<dim3(1152), dim3(256), 0, stream>>>(Rp, Lp, outp);
  phase3_k<<<dim3(2304), dim3(256), 0, stream>>>(outp, ton_w, ton_b, wb + 5*16384, out_b, gate, (float*)d_out);
}

// Round 15
// 169.288 us; speedup vs baseline: 1.0778x; 1.0023x over previous
//
#include <hip/hip_runtime.h>
#include <stdint.h>

typedef unsigned short u16;
typedef short bf16x8 __attribute__((ext_vector_type(8)));
typedef short bf16x4 __attribute__((ext_vector_type(4)));
typedef float f32x4 __attribute__((ext_vector_type(4)));

#define NN 384
#define DIMC 128
#define NPOS (NN*NN)
#define EPSV 1e-5f
#define LNS 136   // xn LDS row stride in u16

__device__ __forceinline__ u16 f2b(float f){
  union { float f; uint32_t u; } v; v.f = f;
  return (u16)((v.u + 0x7FFFu + ((v.u >> 16) & 1u)) >> 16);
}
__device__ __forceinline__ float b2f(u16 h){
  union { uint32_t u; float f; } v; v.u = ((uint32_t)h) << 16;
  return v.f;
}
__device__ __forceinline__ float sigm(float z){
  return __builtin_amdgcn_rcpf(1.0f + __expf(-z));
}

__device__ __forceinline__ void glds16(const u16* g, u16* l){
  __builtin_amdgcn_global_load_lds((const __attribute__((address_space(1))) void*)(g),
                                   (__attribute__((address_space(3))) void*)(l), 16, 0, 0);
}

// ---------------- kernel 0: fp32 -> bf16 weight conversion ----------------
__global__ void wconv_k(const float* __restrict__ s0, const float* __restrict__ s1,
                        const float* __restrict__ s2, const float* __restrict__ s3,
                        const float* __restrict__ s4, const float* __restrict__ s5,
                        u16* __restrict__ dst){
  int bid = blockIdx.x;
  int m = bid >> 6;
  int off = ((bid & 63) << 8) + threadIdx.x;
  const float* src = s0;
  if (m==1) src=s1; else if (m==2) src=s2; else if (m==3) src=s3;
  else if (m==4) src=s4; else if (m==5) src=s5;
  dst[(m<<14) + off] = f2b(src[off]);
}

// ---------------- kernel 1: LN + 5 projections (r11 config) ----------------
// block: fixed second-index c (j), 64 first-index rows r0..r0+63 (i), 4 waves.
// L/R passes: mfma(A=w, B=xn) -> D[e][p]; direct coalesced stores -> [e][j][k=i].
// O pass: mfma(A=w, B=xn) -> D[e][p]; LDS-transpose (reusing xn) -> gate[i][j][e].
__global__ __launch_bounds__(256) void proj_k(
    const float* __restrict__ x, const float* __restrict__ nw, const float* __restrict__ nb,
    const u16* __restrict__ wb,
    const float* __restrict__ left_b, const float* __restrict__ lgate_b,
    const float* __restrict__ right_b, const float* __restrict__ rgate_b,
    const float* __restrict__ ogate_b,
    u16* __restrict__ Lp, u16* __restrict__ Rp, u16* __restrict__ gate)
{
  __shared__ u16 xn[64*LNS];     // 17408 B (reused as transpose buffer in O pass)
  const int tid = threadIdx.x, lane = tid & 63, wid = tid >> 6;
  const int bid = blockIdx.x;
  const int c = bid % NN, r0 = (bid / NN) * 64;
  const int l15 = lane & 15, lg = lane >> 4;

  // ---- LN: 16 lanes per position, 8 ch each ----
  {
    float4 w0 = *(const float4*)(nw + l15*8);
    float4 w1 = *(const float4*)(nw + l15*8 + 4);
    float4 bb0 = *(const float4*)(nb + l15*8);
    float4 bb1 = *(const float4*)(nb + l15*8 + 4);
    float4 v0[4], v1[4];
    #pragma unroll
    for (int it = 0; it < 4; ++it){
      int p = wid*16 + it*4 + lg;
      const float* xp = x + ((size_t)(r0 + p)*NN + c)*DIMC + l15*8;
      v0[it] = *(const float4*)xp;
      v1[it] = *(const float4*)(xp + 4);
    }
    #pragma unroll
    for (int it = 0; it < 4; ++it){
      int p = wid*16 + it*4 + lg;
      float s  = (v0[it].x+v0[it].y)+(v0[it].z+v0[it].w)+((v1[it].x+v1[it].y)+(v1[it].z+v1[it].w));
      float sq = v0[it].x*v0[it].x+v0[it].y*v0[it].y+v0[it].z*v0[it].z+v0[it].w*v0[it].w
               + v1[it].x*v1[it].x+v1[it].y*v1[it].y+v1[it].z*v1[it].z+v1[it].w*v1[it].w;
      #pragma unroll
      for (int o = 8; o; o >>= 1){ s += __shfl_xor(s, o); sq += __shfl_xor(sq, o); }
      float mean = s * (1.0f/128.0f);
      float var  = sq * (1.0f/128.0f) - mean*mean;
      float inv  = rsqrtf(var + EPSV);
      bf16x8 o8;
      o8[0] = (short)f2b((v0[it].x - mean)*inv*w0.x + bb0.x);
      o8[1] = (short)f2b((v0[it].y - mean)*inv*w0.y + bb0.y);
      o8[2] = (short)f2b((v0[it].z - mean)*inv*w0.z + bb0.z);
      o8[3] = (short)f2b((v0[it].w - mean)*inv*w0.w + bb0.w);
      o8[4] = (short)f2b((v1[it].x - mean)*inv*w1.x + bb1.x);
      o8[5] = (short)f2b((v1[it].y - mean)*inv*w1.y + bb1.y);
      o8[6] = (short)f2b((v1[it].z - mean)*inv*w1.z + bb1.z);
      o8[7] = (short)f2b((v1[it].w - mean)*inv*w1.w + bb1.w);
      *(bf16x8*)(xn + p*LNS + l15*8) = o8;
    }
  }
  __syncthreads();

  const int kofs = lg * 8;
  const int wrow = (wid*32 + l15) * 128;
  const int xrowbase = l15 * LNS;

  // ---- passes 0/1: value*sigmoid(gate) -> Lp / Rp ----
  #pragma unroll
  for (int pr = 0; pr < 2; ++pr){
    const u16* wV = wb + (pr*2 + 0)*16384;
    const u16* wG = wb + (pr*2 + 1)*16384;
    const float* bV = pr ? right_b : left_b;
    const float* bG = pr ? rgate_b : lgate_b;
    u16* dst = pr ? Rp : Lp;

    f32x4 aV[2][4], aG[2][4];
    #pragma unroll
    for (int n = 0; n < 2; ++n)
      #pragma unroll
      for (int pt = 0; pt < 4; ++pt){ aV[n][pt] = {0.f,0.f,0.f,0.f}; aG[n][pt] = {0.f,0.f,0.f,0.f}; }

    #pragma unroll
    for (int ks = 0; ks < 4; ++ks){
      bf16x8 xf[4];
      #pragma unroll
      for (int pt = 0; pt < 4; ++pt)
        xf[pt] = *(const bf16x8*)(xn + xrowbase + pt*16*LNS + ks*32 + kofs);
      #pragma unroll
      for (int n = 0; n < 2; ++n){
        bf16x8 wv = *(const bf16x8*)(wV + wrow + n*16*128 + ks*32 + kofs);
        bf16x8 wg = *(const bf16x8*)(wG + wrow + n*16*128 + ks*32 + kofs);
        #pragma unroll
        for (int pt = 0; pt < 4; ++pt){
          aV[n][pt] = __builtin_amdgcn_mfma_f32_16x16x32_bf16(wv, xf[pt], aV[n][pt], 0, 0, 0);
          aG[n][pt] = __builtin_amdgcn_mfma_f32_16x16x32_bf16(wg, xf[pt], aG[n][pt], 0, 0, 0);
        }
      }
    }
    #pragma unroll
    for (int n = 0; n < 2; ++n){
      int ebase = wid*32 + n*16 + lg*4;
      float4 bv4 = *(const float4*)(bV + ebase);
      float4 bg4 = *(const float4*)(bG + ebase);
      #pragma unroll
      for (int r = 0; r < 4; ++r){
        float bv = r==0?bv4.x : r==1?bv4.y : r==2?bv4.z : bv4.w;
        float bg = r==0?bg4.x : r==1?bg4.y : r==2?bg4.z : bg4.w;
        u16* base = dst + (size_t)(ebase + r)*NPOS + (size_t)c*NN + r0 + l15;
        #pragma unroll
        for (int pt = 0; pt < 4; ++pt){
          float v = (aV[n][pt][r] + bv) * sigm(aG[n][pt][r] + bg);
          base[pt*16] = f2b(v);
        }
      }
    }
  }

  // ---- pass 2: ogate -> sigmoid -> gate[i][j][e] via LDS transpose (reuse xn) ----
  {
    const u16* wO = wb + 4*16384;
    f32x4 aO[2][4];
    #pragma unroll
    for (int n = 0; n < 2; ++n)
      #pragma unroll
      for (int pt = 0; pt < 4; ++pt) aO[n][pt] = {0.f,0.f,0.f,0.f};

    #pragma unroll
    for (int ks = 0; ks < 4; ++ks){
      bf16x8 xf[4];
      #pragma unroll
      for (int pt = 0; pt < 4; ++pt)
        xf[pt] = *(const bf16x8*)(xn + xrowbase + pt*16*LNS + ks*32 + kofs);
      #pragma unroll
      for (int n = 0; n < 2; ++n){
        bf16x8 wo = *(const bf16x8*)(wO + wrow + n*16*128 + ks*32 + kofs);
        #pragma unroll
        for (int pt = 0; pt < 4; ++pt)
          aO[n][pt] = __builtin_amdgcn_mfma_f32_16x16x32_bf16(wo, xf[pt], aO[n][pt], 0, 0, 0);
      }
    }
    __syncthreads();   // all waves done reading xn -> safe to overwrite
    #pragma unroll
    for (int n = 0; n < 2; ++n){
      int ebase = wid*32 + n*16 + lg*4;
      float4 bo4 = *(const float4*)(ogate_b + ebase);
      #pragma unroll
      for (int r = 0; r < 4; ++r){
        float bo = r==0?bo4.x : r==1?bo4.y : r==2?bo4.z : bo4.w;
        #pragma unroll
        for (int pt = 0; pt < 4; ++pt)
          xn[(pt*16 + l15)*LNS + ebase + r] = f2b(sigm(aO[n][pt][r] + bo));
      }
    }
    __syncthreads();
    #pragma unroll
    for (int it = 0; it < 4; ++it){
      int idx = tid + it*256;
      int p = idx >> 4, s = idx & 15;
      *(bf16x8*)(gate + ((size_t)(r0 + p)*NN + c)*DIMC + s*8) = *(const bf16x8*)(xn + p*LNS + s*8);
    }
  }
}

// ---------------- kernel 2: triangle einsum, BK=64, global_load_lds + XOR swizzle ----------------
// XCD-aware block remap: all 9 tiles of one d stay on one XCD (panel reuse in its L2).
__global__ __launch_bounds__(256) void phase2_k(const u16* __restrict__ Rp, const u16* __restrict__ Lp,
                                                u16* __restrict__ outp){
  __shared__ u16 lds[17408];
  u16* At = lds;
  u16* Bt = lds + 8192;
  const int tid = threadIdx.x, lane = tid & 63, wid = tid >> 6;
  const int bid = blockIdx.x;
  // bijective remap: 1152 = 8 XCDs x 16 d x 9 tiles
  const int xcd = bid & 7, kk = bid >> 3;
  const int d = xcd*16 + kk/9, tile = kk % 9;
  const int i0 = (tile/3)*128, j0 = (tile%3)*128;
  const int wm = wid >> 1, wn = wid & 1;
  const int iw = wm*64, jw = wn*64;
  const int l15 = lane & 15, lg = lane >> 4;
  const int rmask = l15 & 7;

  int srcoff[4];
  #pragma unroll
  for (int cc = 0; cc < 4; ++cc){
    int idx = wid*256 + cc*64 + lane;
    int row = idx >> 3, slot = idx & 7;
    srcoff[cc] = row*NN + ((slot ^ (row & 7)) * 8);
  }

  f32x4 acc[4][4];
  #pragma unroll
  for (int m = 0; m < 4; ++m)
    #pragma unroll
    for (int n = 0; n < 4; ++n) acc[m][n] = {0.f,0.f,0.f,0.f};

  const u16* Rt0 = Rp + (size_t)d*NPOS + (size_t)i0*NN;
  const u16* Lt0 = Lp + (size_t)d*NPOS + (size_t)j0*NN;

  for (int k0 = 0; k0 < NN; k0 += 64){
    __syncthreads();
    #pragma unroll
    for (int cc = 0; cc < 4; ++cc){
      glds16(Rt0 + k0 + srcoff[cc], At + (wid*4 + cc)*512);
      glds16(Lt0 + k0 + srcoff[cc], Bt + (wid*4 + cc)*512);
    }
    asm volatile("s_waitcnt vmcnt(0)" ::: "memory");
    __syncthreads();
    #pragma unroll
    for (int ks = 0; ks < 2; ++ks){
      int sl = ((ks*4 + lg) ^ rmask) * 8;
      bf16x8 af[4], bfr[4];
      #pragma unroll
      for (int m = 0; m < 4; ++m)
        af[m] = *(const bf16x8*)(At + (iw + m*16 + l15)*64 + sl);
      #pragma unroll
      for (int n = 0; n < 4; ++n)
        bfr[n] = *(const bf16x8*)(Bt + (jw + n*16 + l15)*64 + sl);
      #pragma unroll
      for (int m = 0; m < 4; ++m)
        #pragma unroll
        for (int n = 0; n < 4; ++n)
          acc[m][n] = __builtin_amdgcn_mfma_f32_16x16x32_bf16(af[m], bfr[n], acc[m][n], 0, 0, 0);
    }
  }

  __syncthreads();
  #pragma unroll
  for (int m = 0; m < 4; ++m)
    #pragma unroll
    for (int n = 0; n < 4; ++n)
      #pragma unroll
      for (int r = 0; r < 4; ++r)
        lds[(iw + m*16 + lg*4 + r)*136 + jw + n*16 + l15] = f2b(acc[m][n][r]);
  __syncthreads();
  u16* ob = outp + (size_t)d*NPOS;
  #pragma unroll
  for (int it = 0; it < 8; ++it){
    int idx = tid + it*256;
    int i = idx >> 4, s = idx & 15;
    *(bf16x8*)(ob + (size_t)(i0 + i)*NN + j0 + s*8) = *(const bf16x8*)(lds + i*136 + s*8);
  }
}

// ---------------- kernel 3: LN + out-projection + gate, ZERO LDS / ZERO barriers ----------------
// block: fixed i, 64 consecutive j. Lane (l15,lg) of wave w owns position j = j0+w*16+l15
// and channels h = ks*32 + lg*8 + e -- exactly the MFMA A-fragment layout, loaded directly.
// LN reduce over h: in-lane 32-sum + shfl_xor(16) + shfl_xor(32) across lg-groups (same j).
__global__ __launch_bounds__(256) void phase3_k(const u16* __restrict__ outp,
    const float* __restrict__ tonw, const float* __restrict__ tonb,
    const u16* __restrict__ wOut, const float* __restrict__ out_b,
    const u16* __restrict__ gate, float* __restrict__ out)
{
  const int tid = threadIdx.x, lane = tid & 63, wid = tid >> 6;
  const int bid = blockIdx.x;
  const int i = bid % NN, j0 = (bid / NN) * 64;
  const int l15 = lane & 15, lg = lane >> 4;

  // fragment-order loads + LN statistics
  const u16* ob = outp + (size_t)i*NN + j0 + wid*16 + l15;
  float rv[4][8];
  float s = 0.f, sq = 0.f;
  #pragma unroll
  for (int ks = 0; ks < 4; ++ks){
    #pragma unroll
    for (int e = 0; e < 8; ++e){
      int h = ks*32 + lg*8 + e;
      float v = b2f(ob[(size_t)h*NPOS]);
      rv[ks][e] = v; s += v; sq += v*v;
    }
  }
  s += __shfl_xor(s, 16); sq += __shfl_xor(sq, 16);
  s += __shfl_xor(s, 32); sq += __shfl_xor(sq, 32);
  const float m  = s * (1.f/128.f);
  const float var = sq * (1.f/128.f) - m*m;
  const float inv = rsqrtf(var + EPSV);

  // normalize into A-fragments (bf16)
  bf16x8 af[4];
  #pragma unroll
  for (int ks = 0; ks < 4; ++ks){
    const float* wp = tonw + ks*32 + lg*8;
    const float* bp = tonb + ks*32 + lg*8;
    float4 w0 = *(const float4*)wp;
    float4 w1 = *(const float4*)(wp + 4);
    float4 b0 = *(const float4*)bp;
    float4 b1 = *(const float4*)(bp + 4);
    af[ks][0] = (short)f2b((rv[ks][0] - m)*inv*w0.x + b0.x);
    af[ks][1] = (short)f2b((rv[ks][1] - m)*inv*w0.y + b0.y);
    af[ks][2] = (short)f2b((rv[ks][2] - m)*inv*w0.z + b0.z);
    af[ks][3] = (short)f2b((rv[ks][3] - m)*inv*w0.w + b0.w);
    af[ks][4] = (short)f2b((rv[ks][4] - m)*inv*w1.x + b1.x);
    af[ks][5] = (short)f2b((rv[ks][5] - m)*inv*w1.y + b1.y);
    af[ks][6] = (short)f2b((rv[ks][6] - m)*inv*w1.z + b1.z);
    af[ks][7] = (short)f2b((rv[ks][7] - m)*inv*w1.w + b1.w);
  }

  // out-projection GEMM
  const int kofs = lg * 8;
  f32x4 acc[8];
  #pragma unroll
  for (int n = 0; n < 8; ++n) acc[n] = {0.f,0.f,0.f,0.f};
  #pragma unroll
  for (int ks = 0; ks < 4; ++ks){
    #pragma unroll
    for (int n = 0; n < 8; ++n){
      bf16x8 bm = *(const bf16x8*)(wOut + (n*16 + l15)*128 + ks*32 + kofs);
      acc[n] = __builtin_amdgcn_mfma_f32_16x16x32_bf16(af[ks], bm, acc[n], 0, 0, 0);
    }
  }

  // epilogue: bias + gate (gate[i][j][e], e-contiguous)
  #pragma unroll
  for (int n = 0; n < 8; ++n){
    int dd = n*16 + l15;
    float bo = out_b[dd];
    #pragma unroll
    for (int r = 0; r < 4; ++r){
      int p = wid*16 + lg*4 + r;
      size_t base = ((size_t)i*NN + j0 + p)*DIMC + dd;
      float g = b2f(gate[base]);
      out[base] = (acc[n][r] + bo) * g;
    }
  }
}

extern "C" void kernel_launch(void* const* d_in, const int* in_sizes, int n_in,
                              void* d_out, int out_size, void* d_ws, size_t ws_size,
                              hipStream_t stream){
  const float* x       = (const float*)d_in[0];
  const float* norm_w  = (const float*)d_in[1];
  const float* norm_b  = (const float*)d_in[2];
  const float* left_w  = (const float*)d_in[3];
  const float* left_b  = (const float*)d_in[4];
  const float* right_w = (const float*)d_in[5];
  const float* right_b = (const float*)d_in[6];
  const float* lgate_w = (const float*)d_in[7];
  const float* lgate_b = (const float*)d_in[8];
  const float* rgate_w = (const float*)d_in[9];
  const float* rgate_b = (const float*)d_in[10];
  const float* ogate_w = (const float*)d_in[11];
  const float* ogate_b = (const float*)d_in[12];
  const float* ton_w   = (const float*)d_in[13];
  const float* ton_b   = (const float*)d_in[14];
  const float* out_w   = (const float*)d_in[15];
  const float* out_b   = (const float*)d_in[16];

  char* ws = (char*)d_ws;
  const size_t SZ = (size_t)NPOS * DIMC * sizeof(u16);
  u16* Lp   = (u16*)(ws);
  u16* Rp   = (u16*)(ws + SZ);
  u16* gate = (u16*)(ws + 2*SZ);
  u16* outp = (u16*)(ws + 3*SZ);
  u16* wb   = (u16*)(ws + 4*SZ);

  wconv_k<<<dim3(384), dim3(256), 0, stream>>>(left_w, lgate_w, right_w, rgate_w, ogate_w, out_w, wb);
  proj_k<<<dim3(2304), dim3(256), 0, stream>>>(x, norm_w, norm_b, wb,
      left_b, lgate_b, right_b, rgate_b, ogate_b, Lp, Rp, gate);
  phase2_k<<<dim3(1152), dim3(256), 0, stream>>>(Rp, Lp, outp);
  phase3_k<<<dim3(2304), dim3(256), 0, stream>>>(outp, ton_w, ton_b, wb + 5*16384, out_b, gate, (float*)d_out);
}

// Round 16
// 167.697 us; speedup vs baseline: 1.0880x; 1.0095x over previous
//
#include <hip/hip_runtime.h>
#include <stdint.h>

typedef unsigned short u16;
typedef short bf16x8 __attribute__((ext_vector_type(8)));
typedef short bf16x4 __attribute__((ext_vector_type(4)));
typedef float f32x4 __attribute__((ext_vector_type(4)));

#define NN 384
#define DIMC 128
#define NPOS (NN*NN)
#define EPSV 1e-5f

__device__ __forceinline__ u16 f2b(float f){
  union { float f; uint32_t u; } v; v.f = f;
  return (u16)((v.u + 0x7FFFu + ((v.u >> 16) & 1u)) >> 16);
}
__device__ __forceinline__ float b2f(u16 h){
  union { uint32_t u; float f; } v; v.u = ((uint32_t)h) << 16;
  return v.f;
}
__device__ __forceinline__ float sigm(float z){
  return __builtin_amdgcn_rcpf(1.0f + __expf(-z));
}
__device__ __forceinline__ void glds16(const u16* g, u16* l){
  __builtin_amdgcn_global_load_lds((const __attribute__((address_space(1))) void*)(g),
                                   (__attribute__((address_space(3))) void*)(l), 16, 0, 0);
}

// ---------------- kernel 0: fp32 -> bf16 weights, V/G pair-interleaved ----------------
// tiles (128x128 u16): [0]=L-pair half0 [1]=L-pair half1 [2]=R-pair half0 [3]=R-pair half1
// [4]=ogate [5]=out_w.  Pair tile row 2a = value_w[half*64+a], row 2a+1 = gate_w[half*64+a].
__global__ void wconv_k(const float* __restrict__ s_l, const float* __restrict__ s_lg,
                        const float* __restrict__ s_r, const float* __restrict__ s_rg,
                        const float* __restrict__ s_o, const float* __restrict__ s_ow,
                        u16* __restrict__ dst){
  int bid = blockIdx.x;
  int m = bid >> 6;                       // 0..5
  int off = ((bid & 63) << 8) + threadIdx.x;
  float v;
  if (m < 4){
    int r = off >> 7, ch = off & 127;
    int a = ((m & 1) << 6) + (r >> 1);
    const float* src = (m < 2) ? ((r & 1) ? s_lg : s_l) : ((r & 1) ? s_rg : s_r);
    v = src[(a << 7) + ch];
  } else if (m == 4) v = s_o[off];
  else v = s_ow[off];
  dst[(m << 14) + off] = f2b(v);
}

// ---------------- kernel 1a: LayerNorm streamer -> xn_g[j][i][ch] bf16 ----------------
__global__ __launch_bounds__(256) void ln_k(
    const float* __restrict__ x, const float* __restrict__ nw, const float* __restrict__ nb,
    u16* __restrict__ xng)
{
  const int tid = threadIdx.x, lane = tid & 63, wid = tid >> 6;
  const int bid = blockIdx.x;
  const int c = bid % NN, r0 = (bid / NN) * 64;
  const int l15 = lane & 15, lg = lane >> 4;

  float4 w0 = *(const float4*)(nw + l15*8);
  float4 w1 = *(const float4*)(nw + l15*8 + 4);
  float4 bb0 = *(const float4*)(nb + l15*8);
  float4 bb1 = *(const float4*)(nb + l15*8 + 4);
  float4 v0[4], v1[4];
  #pragma unroll
  for (int it = 0; it < 4; ++it){
    int p = wid*16 + it*4 + lg;
    const float* xp = x + ((size_t)(r0 + p)*NN + c)*DIMC + l15*8;
    v0[it] = *(const float4*)xp;
    v1[it] = *(const float4*)(xp + 4);
  }
  #pragma unroll
  for (int it = 0; it < 4; ++it){
    int p = wid*16 + it*4 + lg;
    float s  = (v0[it].x+v0[it].y)+(v0[it].z+v0[it].w)+((v1[it].x+v1[it].y)+(v1[it].z+v1[it].w));
    float sq = v0[it].x*v0[it].x+v0[it].y*v0[it].y+v0[it].z*v0[it].z+v0[it].w*v0[it].w
             + v1[it].x*v1[it].x+v1[it].y*v1[it].y+v1[it].z*v1[it].z+v1[it].w*v1[it].w;
    #pragma unroll
    for (int o = 8; o; o >>= 1){ s += __shfl_xor(s, o); sq += __shfl_xor(sq, o); }
    float mean = s * (1.0f/128.0f);
    float var  = sq * (1.0f/128.0f) - mean*mean;
    float inv  = rsqrtf(var + EPSV);
    bf16x8 o8;
    o8[0] = (short)f2b((v0[it].x - mean)*inv*w0.x + bb0.x);
    o8[1] = (short)f2b((v0[it].y - mean)*inv*w0.y + bb0.y);
    o8[2] = (short)f2b((v0[it].z - mean)*inv*w0.z + bb0.z);
    o8[3] = (short)f2b((v0[it].w - mean)*inv*w0.w + bb0.w);
    o8[4] = (short)f2b((v1[it].x - mean)*inv*w1.x + bb1.x);
    o8[5] = (short)f2b((v1[it].y - mean)*inv*w1.y + bb1.y);
    o8[6] = (short)f2b((v1[it].z - mean)*inv*w1.z + bb1.z);
    o8[7] = (short)f2b((v1[it].w - mean)*inv*w1.w + bb1.w);
    *(bf16x8*)(xng + ((size_t)c*NN + r0 + p)*DIMC + l15*8) = o8;
  }
}

// ---------------- kernel 1b: projection GEMM, 128x128 tiles, K=128 single-stage ----------------
// grid 5760 = 8 XCD x 720 (bijective). nt = n-tile (1152), t = m-tile (5).
// A = weight tile, B = xn rows, both LDS via XOR-swizzled glds16. 4 waves, 64x64 each.
// t<4: acc r = (V_q, G_q, V_{q+1}, G_{q+1}) -> fused sigmoid; t=4: ogate -> LDS transpose -> gate[j][i][e].
__global__ __launch_bounds__(256) void projB_k(const u16* __restrict__ xng, const u16* __restrict__ wb2,
    const float* __restrict__ left_b, const float* __restrict__ lgate_b,
    const float* __restrict__ right_b, const float* __restrict__ rgate_b,
    const float* __restrict__ ogate_b,
    u16* __restrict__ Lp, u16* __restrict__ Rp, u16* __restrict__ gate)
{
  __shared__ u16 lds[32768];          // 65536 B: A [0,16384), B [16384,32768)
  u16* Asl = lds;
  u16* Bsl = lds + 16384;
  const int tid = threadIdx.x, lane = tid & 63, wid = tid >> 6;
  const int bid = blockIdx.x;
  const int xcd = bid & 7, idx = bid >> 3;
  const int g = xcd*720 + idx;
  const int nt = g / 5, t = g % 5;
  const int c = nt / 3, r0 = (nt % 3) * 128;
  const size_t posbase = (size_t)c*NN + r0;
  const int l15 = lane & 15, lg = lane >> 4;
  const int wm = wid >> 1, wn = wid & 1;

  const u16* Aw = wb2 + t*16384;
  const u16* Bx = xng + posbase*DIMC;
  #pragma unroll
  for (int it = 0; it < 8; ++it){
    int cidx = it*256 + tid;
    int row = cidx >> 4, sl = cidx & 15;
    int so = row*128 + ((sl ^ (row & 15)) * 8);
    glds16(Aw + so, Asl + cidx*8);
    glds16(Bx + so, Bsl + cidx*8);
  }
  asm volatile("s_waitcnt vmcnt(0)" ::: "memory");
  __syncthreads();

  f32x4 acc[4][4];
  #pragma unroll
  for (int m = 0; m < 4; ++m)
    #pragma unroll
    for (int n = 0; n < 4; ++n) acc[m][n] = {0.f,0.f,0.f,0.f};

  #pragma unroll
  for (int ks = 0; ks < 4; ++ks){
    int sl = ((ks*4 + lg) ^ l15) * 8;
    bf16x8 af[4], bfr[4];
    #pragma unroll
    for (int m = 0; m < 4; ++m)
      af[m] = *(const bf16x8*)(Asl + (wm*64 + m*16 + l15)*128 + sl);
    #pragma unroll
    for (int n = 0; n < 4; ++n)
      bfr[n] = *(const bf16x8*)(Bsl + (wn*64 + n*16 + l15)*128 + sl);
    #pragma unroll
    for (int m = 0; m < 4; ++m)
      #pragma unroll
      for (int n = 0; n < 4; ++n)
        acc[m][n] = __builtin_amdgcn_mfma_f32_16x16x32_bf16(af[m], bfr[n], acc[m][n], 0, 0, 0);
  }

  if (t < 4){
    u16* dst = (t < 2) ? Lp : Rp;
    const float* bV = (t < 2) ? left_b : right_b;
    const float* bG = (t < 2) ? lgate_b : rgate_b;
    const int th = t & 1;
    #pragma unroll
    for (int m = 0; m < 4; ++m){
      int e0 = th*64 + wm*32 + m*8 + lg*2;
      float2 bv2 = *(const float2*)(bV + e0);
      float2 bg2 = *(const float2*)(bG + e0);
      #pragma unroll
      for (int n = 0; n < 4; ++n){
        size_t pp = posbase + wn*64 + n*16 + l15;
        float o0 = (acc[m][n][0] + bv2.x) * sigm(acc[m][n][1] + bg2.x);
        float o1 = (acc[m][n][2] + bv2.y) * sigm(acc[m][n][3] + bg2.y);
        dst[(size_t)e0*NPOS + pp]     = f2b(o0);
        dst[(size_t)(e0+1)*NPOS + pp] = f2b(o1);
      }
    }
  } else {
    __syncthreads();   // done reading A/B tiles -> reuse lds as [128 pos][136] transpose buf
    #pragma unroll
    for (int m = 0; m < 4; ++m){
      int e = wm*64 + m*16 + lg*4;
      float4 bo4 = *(const float4*)(ogate_b + e);
      #pragma unroll
      for (int n = 0; n < 4; ++n){
        int pl = wn*64 + n*16 + l15;
        bf16x4 o4;
        o4[0] = (short)f2b(sigm(acc[m][n][0] + bo4.x));
        o4[1] = (short)f2b(sigm(acc[m][n][1] + bo4.y));
        o4[2] = (short)f2b(sigm(acc[m][n][2] + bo4.z));
        o4[3] = (short)f2b(sigm(acc[m][n][3] + bo4.w));
        *(bf16x4*)(lds + pl*136 + e) = o4;
      }
    }
    __syncthreads();
    #pragma unroll
    for (int it = 0; it < 8; ++it){
      int cidx = it*256 + tid;
      int row = cidx >> 4, s = cidx & 15;
      *(bf16x8*)(gate + (posbase + row)*DIMC + s*8) = *(const bf16x8*)(lds + row*136 + s*8);
    }
  }
}

// ---------------- kernel 2: triangle einsum, BK=64, global_load_lds + XOR swizzle ----------------
__global__ __launch_bounds__(256) void phase2_k(const u16* __restrict__ Rp, const u16* __restrict__ Lp,
                                                u16* __restrict__ outp){
  __shared__ u16 lds[17408];
  u16* At = lds;
  u16* Bt = lds + 8192;
  const int tid = threadIdx.x, lane = tid & 63, wid = tid >> 6;
  const int bid = blockIdx.x;
  const int xcd = bid & 7, kk = bid >> 3;
  const int d = xcd*16 + kk/9, tile = kk % 9;
  const int i0 = (tile/3)*128, j0 = (tile%3)*128;
  const int wm = wid >> 1, wn = wid & 1;
  const int iw = wm*64, jw = wn*64;
  const int l15 = lane & 15, lg = lane >> 4;
  const int rmask = l15 & 7;

  int srcoff[4];
  #pragma unroll
  for (int cc = 0; cc < 4; ++cc){
    int idx = wid*256 + cc*64 + lane;
    int row = idx >> 3, slot = idx & 7;
    srcoff[cc] = row*NN + ((slot ^ (row & 7)) * 8);
  }

  f32x4 acc[4][4];
  #pragma unroll
  for (int m = 0; m < 4; ++m)
    #pragma unroll
    for (int n = 0; n < 4; ++n) acc[m][n] = {0.f,0.f,0.f,0.f};

  const u16* Rt0 = Rp + (size_t)d*NPOS + (size_t)i0*NN;
  const u16* Lt0 = Lp + (size_t)d*NPOS + (size_t)j0*NN;

  for (int k0 = 0; k0 < NN; k0 += 64){
    __syncthreads();
    #pragma unroll
    for (int cc = 0; cc < 4; ++cc){
      glds16(Rt0 + k0 + srcoff[cc], At + (wid*4 + cc)*512);
      glds16(Lt0 + k0 + srcoff[cc], Bt + (wid*4 + cc)*512);
    }
    asm volatile("s_waitcnt vmcnt(0)" ::: "memory");
    __syncthreads();
    #pragma unroll
    for (int ks = 0; ks < 2; ++ks){
      int sl = ((ks*4 + lg) ^ rmask) * 8;
      bf16x8 af[4], bfr[4];
      #pragma unroll
      for (int m = 0; m < 4; ++m)
        af[m] = *(const bf16x8*)(At + (iw + m*16 + l15)*64 + sl);
      #pragma unroll
      for (int n = 0; n < 4; ++n)
        bfr[n] = *(const bf16x8*)(Bt + (jw + n*16 + l15)*64 + sl);
      #pragma unroll
      for (int m = 0; m < 4; ++m)
        #pragma unroll
        for (int n = 0; n < 4; ++n)
          acc[m][n] = __builtin_amdgcn_mfma_f32_16x16x32_bf16(af[m], bfr[n], acc[m][n], 0, 0, 0);
    }
  }

  __syncthreads();
  #pragma unroll
  for (int m = 0; m < 4; ++m)
    #pragma unroll
    for (int n = 0; n < 4; ++n)
      #pragma unroll
      for (int r = 0; r < 4; ++r)
        lds[(iw + m*16 + lg*4 + r)*136 + jw + n*16 + l15] = f2b(acc[m][n][r]);
  __syncthreads();
  u16* ob = outp + (size_t)d*NPOS;
  #pragma unroll
  for (int it = 0; it < 8; ++it){
    int idx = tid + it*256;
    int i = idx >> 4, s = idx & 15;
    *(bf16x8*)(ob + (size_t)(i0 + i)*NN + j0 + s*8) = *(const bf16x8*)(lds + i*136 + s*8);
  }
}

// ---------------- kernel 3: LN + out-projection + gate (r11 LDS version, gate[j][i][e]) ----------------
__global__ __launch_bounds__(256) void phase3_k(const u16* __restrict__ outp,
    const float* __restrict__ tonw, const float* __restrict__ tonb,
    const u16* __restrict__ wOut, const float* __restrict__ out_b,
    const u16* __restrict__ gate, float* __restrict__ out)
{
  __shared__ u16 xn2[64*132];
  __shared__ float reds[4][64], redq[4][64];
  __shared__ float marr[64], iarr[64];
  const int tid = threadIdx.x, lane = tid & 63, wid = tid >> 6;
  const int bid = blockIdx.x;
  const int i = bid % NN, j0 = (bid / NN) * 64;
  const int l15 = lane & 15, lg = lane >> 4;

  float rv[32];
  float s = 0.f, sq = 0.f;
  #pragma unroll
  for (int q = 0; q < 32; ++q){
    int h = wid*32 + q;
    float v = b2f(outp[(size_t)h*NPOS + (size_t)i*NN + j0 + lane]);
    rv[q] = v; s += v; sq += v*v;
  }
  reds[wid][lane] = s; redq[wid][lane] = sq;
  __syncthreads();
  if (tid < 64){
    float ts = reds[0][tid] + reds[1][tid] + reds[2][tid] + reds[3][tid];
    float tq = redq[0][tid] + redq[1][tid] + redq[2][tid] + redq[3][tid];
    float m  = ts * (1.f/128.f);
    float var = tq * (1.f/128.f) - m*m;
    marr[tid] = m; iarr[tid] = rsqrtf(var + EPSV);
  }
  __syncthreads();
  float m = marr[lane], inv = iarr[lane];
  #pragma unroll
  for (int q = 0; q < 32; ++q){
    int h = wid*32 + q;
    float v = (rv[q] - m)*inv*tonw[h] + tonb[h];
    xn2[lane*132 + h] = f2b(v);
  }
  __syncthreads();

  f32x4 acc[8];
  #pragma unroll
  for (int n = 0; n < 8; ++n) acc[n] = {0.f,0.f,0.f,0.f};
  const int row = wid*16 + l15;
  const int kofs = lg * 8;
  #pragma unroll
  for (int ks = 0; ks < 4; ++ks){
    const u16* ap = xn2 + row*132 + ks*32 + kofs;
    bf16x4 a0 = *(const bf16x4*)ap;
    bf16x4 a1 = *(const bf16x4*)(ap + 4);
    bf16x8 af = __builtin_shufflevector(a0, a1, 0,1,2,3,4,5,6,7);
    #pragma unroll
    for (int n = 0; n < 8; ++n){
      bf16x8 bm = *(const bf16x8*)(wOut + (n*16 + l15)*128 + ks*32 + kofs);
      acc[n] = __builtin_amdgcn_mfma_f32_16x16x32_bf16(af, bm, acc[n], 0, 0, 0);
    }
  }
  #pragma unroll
  for (int n = 0; n < 8; ++n){
    int dd = n*16 + l15;
    float bo = out_b[dd];
    #pragma unroll
    for (int r = 0; r < 4; ++r){
      int p = wid*16 + lg*4 + r;
      size_t base = ((size_t)i*NN + j0 + p)*DIMC + dd;
      float g = b2f(gate[((size_t)(j0 + p)*NN + i)*DIMC + dd]);
      out[base] = (acc[n][r] + bo) * g;
    }
  }
}

extern "C" void kernel_launch(void* const* d_in, const int* in_sizes, int n_in,
                              void* d_out, int out_size, void* d_ws, size_t ws_size,
                              hipStream_t stream){
  const float* x       = (const float*)d_in[0];
  const float* norm_w  = (const float*)d_in[1];
  const float* norm_b  = (const float*)d_in[2];
  const float* left_w  = (const float*)d_in[3];
  const float* left_b  = (const float*)d_in[4];
  const float* right_w = (const float*)d_in[5];
  const float* right_b = (const float*)d_in[6];
  const float* lgate_w = (const float*)d_in[7];
  const float* lgate_b = (const float*)d_in[8];
  const float* rgate_w = (const float*)d_in[9];
  const float* rgate_b = (const float*)d_in[10];
  const float* ogate_w = (const float*)d_in[11];
  const float* ogate_b = (const float*)d_in[12];
  const float* ton_w   = (const float*)d_in[13];
  const float* ton_b   = (const float*)d_in[14];
  const float* out_w   = (const float*)d_in[15];
  const float* out_b   = (const float*)d_in[16];

  char* ws = (char*)d_ws;
  const size_t SZ = (size_t)NPOS * DIMC * sizeof(u16);
  u16* Lp   = (u16*)(ws);
  u16* Rp   = (u16*)(ws + SZ);
  u16* gate = (u16*)(ws + 2*SZ);
  u16* outp = (u16*)(ws + 3*SZ);
  u16* wb   = (u16*)(ws + 4*SZ);
  u16* xng  = outp;   // xn_g aliases outp: fully consumed by projB before phase2 writes outp

  wconv_k<<<dim3(384), dim3(256), 0, stream>>>(left_w, lgate_w, right_w, rgate_w, ogate_w, out_w, wb);
  ln_k<<<dim3(2304), dim3(256), 0, stream>>>(x, norm_w, norm_b, xng);
  projB_k<<<dim3(5760), dim3(256), 0, stream>>>(xng, wb,
      left_b, lgate_b, right_b, rgate_b, ogate_b, Lp, Rp, gate);
  phase2_k<<<dim3(1152), dim3(256), 0, stream>>>(Rp, Lp, outp);
  phase3_k<<<dim3(2304), dim3(256), 0, stream>>>(outp, ton_w, ton_b, wb + 5*16384, out_b, gate, (float*)d_out);
}

// Round 17
// 163.476 us; speedup vs baseline: 1.1161x; 1.0258x over previous
//
#include <hip/hip_runtime.h>
#include <stdint.h>

typedef unsigned short u16;
typedef short bf16x8 __attribute__((ext_vector_type(8)));
typedef short bf16x4 __attribute__((ext_vector_type(4)));
typedef float f32x4 __attribute__((ext_vector_type(4)));

#define NN 384
#define DIMC 128
#define NPOS (NN*NN)
#define EPSV 1e-5f

__device__ __forceinline__ u16 f2b(float f){
  union { float f; uint32_t u; } v; v.f = f;
  return (u16)((v.u + 0x7FFFu + ((v.u >> 16) & 1u)) >> 16);
}
__device__ __forceinline__ float b2f(u16 h){
  union { uint32_t u; float f; } v; v.u = ((uint32_t)h) << 16;
  return v.f;
}
__device__ __forceinline__ float sigm(float z){
  return __builtin_amdgcn_rcpf(1.0f + __expf(-z));
}
__device__ __forceinline__ void glds16(const u16* g, u16* l){
  __builtin_amdgcn_global_load_lds((const __attribute__((address_space(1))) void*)(g),
                                   (__attribute__((address_space(3))) void*)(l), 16, 0, 0);
}

// ---------------- kernel 0: fp32 -> bf16 weights, V/G pair-interleaved ----------------
// tiles (128x128 u16): [0]=L-pair half0 [1]=L-pair half1 [2]=R-pair half0 [3]=R-pair half1
// [4]=ogate [5]=out_w.  Pair tile row 2a = value_w[half*64+a], row 2a+1 = gate_w[half*64+a].
__global__ void wconv_k(const float* __restrict__ s_l, const float* __restrict__ s_lg,
                        const float* __restrict__ s_r, const float* __restrict__ s_rg,
                        const float* __restrict__ s_o, const float* __restrict__ s_ow,
                        u16* __restrict__ dst){
  int bid = blockIdx.x;
  int m = bid >> 6;                       // 0..5
  int off = ((bid & 63) << 8) + threadIdx.x;
  float v;
  if (m < 4){
    int r = off >> 7, ch = off & 127;
    int a = ((m & 1) << 6) + (r >> 1);
    const float* src = (m < 2) ? ((r & 1) ? s_lg : s_l) : ((r & 1) ? s_rg : s_r);
    v = src[(a << 7) + ch];
  } else if (m == 4) v = s_o[off];
  else v = s_ow[off];
  dst[(m << 14) + off] = f2b(v);
}

// ---------------- kernel 1a: LayerNorm streamer -> xn_g[j][i][ch] bf16 ----------------
__global__ __launch_bounds__(256) void ln_k(
    const float* __restrict__ x, const float* __restrict__ nw, const float* __restrict__ nb,
    u16* __restrict__ xng)
{
  const int tid = threadIdx.x, lane = tid & 63, wid = tid >> 6;
  const int bid = blockIdx.x;
  const int c = bid % NN, r0 = (bid / NN) * 64;
  const int l15 = lane & 15, lg = lane >> 4;

  float4 w0 = *(const float4*)(nw + l15*8);
  float4 w1 = *(const float4*)(nw + l15*8 + 4);
  float4 bb0 = *(const float4*)(nb + l15*8);
  float4 bb1 = *(const float4*)(nb + l15*8 + 4);
  float4 v0[4], v1[4];
  #pragma unroll
  for (int it = 0; it < 4; ++it){
    int p = wid*16 + it*4 + lg;
    const float* xp = x + ((size_t)(r0 + p)*NN + c)*DIMC + l15*8;
    v0[it] = *(const float4*)xp;
    v1[it] = *(const float4*)(xp + 4);
  }
  #pragma unroll
  for (int it = 0; it < 4; ++it){
    int p = wid*16 + it*4 + lg;
    float s  = (v0[it].x+v0[it].y)+(v0[it].z+v0[it].w)+((v1[it].x+v1[it].y)+(v1[it].z+v1[it].w));
    float sq = v0[it].x*v0[it].x+v0[it].y*v0[it].y+v0[it].z*v0[it].z+v0[it].w*v0[it].w
             + v1[it].x*v1[it].x+v1[it].y*v1[it].y+v1[it].z*v1[it].z+v1[it].w*v1[it].w;
    #pragma unroll
    for (int o = 8; o; o >>= 1){ s += __shfl_xor(s, o); sq += __shfl_xor(sq, o); }
    float mean = s * (1.0f/128.0f);
    float var  = sq * (1.0f/128.0f) - mean*mean;
    float inv  = rsqrtf(var + EPSV);
    bf16x8 o8;
    o8[0] = (short)f2b((v0[it].x - mean)*inv*w0.x + bb0.x);
    o8[1] = (short)f2b((v0[it].y - mean)*inv*w0.y + bb0.y);
    o8[2] = (short)f2b((v0[it].z - mean)*inv*w0.z + bb0.z);
    o8[3] = (short)f2b((v0[it].w - mean)*inv*w0.w + bb0.w);
    o8[4] = (short)f2b((v1[it].x - mean)*inv*w1.x + bb1.x);
    o8[5] = (short)f2b((v1[it].y - mean)*inv*w1.y + bb1.y);
    o8[6] = (short)f2b((v1[it].z - mean)*inv*w1.z + bb1.z);
    o8[7] = (short)f2b((v1[it].w - mean)*inv*w1.w + bb1.w);
    *(bf16x8*)(xng + ((size_t)c*NN + r0 + p)*DIMC + l15*8) = o8;
  }
}

// ---------------- kernel 1b: projection GEMM, 128x128 tiles, K=128 single-stage ----------------
// grid 5760 = 8 XCD x 720 (bijective). nt = n-tile (1152), t = m-tile (5).
// A = weight tile, B = xn rows, both LDS via XOR-swizzled glds16. 4 waves, 64x64 each.
// t<4: acc r = (V_q, G_q, V_{q+1}, G_{q+1}) -> fused sigmoid; t=4: ogate -> LDS transpose -> gate[i][j][e].
__global__ __launch_bounds__(256) void projB_k(const u16* __restrict__ xng, const u16* __restrict__ wb2,
    const float* __restrict__ left_b, const float* __restrict__ lgate_b,
    const float* __restrict__ right_b, const float* __restrict__ rgate_b,
    const float* __restrict__ ogate_b,
    u16* __restrict__ Lp, u16* __restrict__ Rp, u16* __restrict__ gate)
{
  __shared__ u16 lds[32768];          // 65536 B: A [0,16384), B [16384,32768)
  u16* Asl = lds;
  u16* Bsl = lds + 16384;
  const int tid = threadIdx.x, lane = tid & 63, wid = tid >> 6;
  const int bid = blockIdx.x;
  const int xcd = bid & 7, idx = bid >> 3;
  const int g = xcd*720 + idx;
  const int nt = g / 5, t = g % 5;
  const int c = nt / 3, r0 = (nt % 3) * 128;
  const size_t posbase = (size_t)c*NN + r0;
  const int l15 = lane & 15, lg = lane >> 4;
  const int wm = wid >> 1, wn = wid & 1;

  const u16* Aw = wb2 + t*16384;
  const u16* Bx = xng + posbase*DIMC;
  #pragma unroll
  for (int it = 0; it < 8; ++it){
    int cidx = it*256 + tid;
    int row = cidx >> 4, sl = cidx & 15;
    int so = row*128 + ((sl ^ (row & 15)) * 8);
    glds16(Aw + so, Asl + cidx*8);
    glds16(Bx + so, Bsl + cidx*8);
  }
  asm volatile("s_waitcnt vmcnt(0)" ::: "memory");
  __syncthreads();

  f32x4 acc[4][4];
  #pragma unroll
  for (int m = 0; m < 4; ++m)
    #pragma unroll
    for (int n = 0; n < 4; ++n) acc[m][n] = {0.f,0.f,0.f,0.f};

  #pragma unroll
  for (int ks = 0; ks < 4; ++ks){
    int sl = ((ks*4 + lg) ^ l15) * 8;
    bf16x8 af[4], bfr[4];
    #pragma unroll
    for (int m = 0; m < 4; ++m)
      af[m] = *(const bf16x8*)(Asl + (wm*64 + m*16 + l15)*128 + sl);
    #pragma unroll
    for (int n = 0; n < 4; ++n)
      bfr[n] = *(const bf16x8*)(Bsl + (wn*64 + n*16 + l15)*128 + sl);
    #pragma unroll
    for (int m = 0; m < 4; ++m)
      #pragma unroll
      for (int n = 0; n < 4; ++n)
        acc[m][n] = __builtin_amdgcn_mfma_f32_16x16x32_bf16(af[m], bfr[n], acc[m][n], 0, 0, 0);
  }

  if (t < 4){
    u16* dst = (t < 2) ? Lp : Rp;
    const float* bV = (t < 2) ? left_b : right_b;
    const float* bG = (t < 2) ? lgate_b : rgate_b;
    const int th = t & 1;
    #pragma unroll
    for (int m = 0; m < 4; ++m){
      int e0 = th*64 + wm*32 + m*8 + lg*2;
      float2 bv2 = *(const float2*)(bV + e0);
      float2 bg2 = *(const float2*)(bG + e0);
      #pragma unroll
      for (int n = 0; n < 4; ++n){
        size_t pp = posbase + wn*64 + n*16 + l15;
        float o0 = (acc[m][n][0] + bv2.x) * sigm(acc[m][n][1] + bg2.x);
        float o1 = (acc[m][n][2] + bv2.y) * sigm(acc[m][n][3] + bg2.y);
        dst[(size_t)e0*NPOS + pp]     = f2b(o0);
        dst[(size_t)(e0+1)*NPOS + pp] = f2b(o1);
      }
    }
  } else {
    __syncthreads();   // done reading A/B tiles -> reuse lds as [128 pos][136] transpose buf
    #pragma unroll
    for (int m = 0; m < 4; ++m){
      int e = wm*64 + m*16 + lg*4;
      float4 bo4 = *(const float4*)(ogate_b + e);
      #pragma unroll
      for (int n = 0; n < 4; ++n){
        int pl = wn*64 + n*16 + l15;
        bf16x4 o4;
        o4[0] = (short)f2b(sigm(acc[m][n][0] + bo4.x));
        o4[1] = (short)f2b(sigm(acc[m][n][1] + bo4.y));
        o4[2] = (short)f2b(sigm(acc[m][n][2] + bo4.z));
        o4[3] = (short)f2b(sigm(acc[m][n][3] + bo4.w));
        *(bf16x4*)(lds + pl*136 + e) = o4;
      }
    }
    __syncthreads();
    // store gate[i][j][e]: row = local i, c = j. 256B contiguous per row, rows strided NN*DIMC.
    #pragma unroll
    for (int it = 0; it < 8; ++it){
      int cidx = it*256 + tid;
      int row = cidx >> 4, s = cidx & 15;
      *(bf16x8*)(gate + ((size_t)(r0 + row)*NN + c)*DIMC + s*8) = *(const bf16x8*)(lds + row*136 + s*8);
    }
  }
}

// ---------------- kernel 2: triangle einsum, BK=64, global_load_lds + XOR swizzle ----------------
__global__ __launch_bounds__(256) void phase2_k(const u16* __restrict__ Rp, const u16* __restrict__ Lp,
                                                u16* __restrict__ outp){
  __shared__ u16 lds[17408];
  u16* At = lds;
  u16* Bt = lds + 8192;
  const int tid = threadIdx.x, lane = tid & 63, wid = tid >> 6;
  const int bid = blockIdx.x;
  const int xcd = bid & 7, kk = bid >> 3;
  const int d = xcd*16 + kk/9, tile = kk % 9;
  const int i0 = (tile/3)*128, j0 = (tile%3)*128;
  const int wm = wid >> 1, wn = wid & 1;
  const int iw = wm*64, jw = wn*64;
  const int l15 = lane & 15, lg = lane >> 4;
  const int rmask = l15 & 7;

  int srcoff[4];
  #pragma unroll
  for (int cc = 0; cc < 4; ++cc){
    int idx = wid*256 + cc*64 + lane;
    int row = idx >> 3, slot = idx & 7;
    srcoff[cc] = row*NN + ((slot ^ (row & 7)) * 8);
  }

  f32x4 acc[4][4];
  #pragma unroll
  for (int m = 0; m < 4; ++m)
    #pragma unroll
    for (int n = 0; n < 4; ++n) acc[m][n] = {0.f,0.f,0.f,0.f};

  const u16* Rt0 = Rp + (size_t)d*NPOS + (size_t)i0*NN;
  const u16* Lt0 = Lp + (size_t)d*NPOS + (size_t)j0*NN;

  for (int k0 = 0; k0 < NN; k0 += 64){
    __syncthreads();
    #pragma unroll
    for (int cc = 0; cc < 4; ++cc){
      glds16(Rt0 + k0 + srcoff[cc], At + (wid*4 + cc)*512);
      glds16(Lt0 + k0 + srcoff[cc], Bt + (wid*4 + cc)*512);
    }
    asm volatile("s_waitcnt vmcnt(0)" ::: "memory");
    __syncthreads();
    #pragma unroll
    for (int ks = 0; ks < 2; ++ks){
      int sl = ((ks*4 + lg) ^ rmask) * 8;
      bf16x8 af[4], bfr[4];
      #pragma unroll
      for (int m = 0; m < 4; ++m)
        af[m] = *(const bf16x8*)(At + (iw + m*16 + l15)*64 + sl);
      #pragma unroll
      for (int n = 0; n < 4; ++n)
        bfr[n] = *(const bf16x8*)(Bt + (jw + n*16 + l15)*64 + sl);
      #pragma unroll
      for (int m = 0; m < 4; ++m)
        #pragma unroll
        for (int n = 0; n < 4; ++n)
          acc[m][n] = __builtin_amdgcn_mfma_f32_16x16x32_bf16(af[m], bfr[n], acc[m][n], 0, 0, 0);
    }
  }

  __syncthreads();
  #pragma unroll
  for (int m = 0; m < 4; ++m)
    #pragma unroll
    for (int n = 0; n < 4; ++n)
      #pragma unroll
      for (int r = 0; r < 4; ++r)
        lds[(iw + m*16 + lg*4 + r)*136 + jw + n*16 + l15] = f2b(acc[m][n][r]);
  __syncthreads();
  u16* ob = outp + (size_t)d*NPOS;
  #pragma unroll
  for (int it = 0; it < 8; ++it){
    int idx = tid + it*256;
    int i = idx >> 4, s = idx & 15;
    *(bf16x8*)(ob + (size_t)(i0 + i)*NN + j0 + s*8) = *(const bf16x8*)(lds + i*136 + s*8);
  }
}

// ---------------- kernel 3: LN + out-projection + gate (r11 version, gate[i][j][e]) ----------------
__global__ __launch_bounds__(256) void phase3_k(const u16* __restrict__ outp,
    const float* __restrict__ tonw, const float* __restrict__ tonb,
    const u16* __restrict__ wOut, const float* __restrict__ out_b,
    const u16* __restrict__ gate, float* __restrict__ out)
{
  __shared__ u16 xn2[64*132];
  __shared__ float reds[4][64], redq[4][64];
  __shared__ float marr[64], iarr[64];
  const int tid = threadIdx.x, lane = tid & 63, wid = tid >> 6;
  const int bid = blockIdx.x;
  const int i = bid % NN, j0 = (bid / NN) * 64;
  const int l15 = lane & 15, lg = lane >> 4;

  float rv[32];
  float s = 0.f, sq = 0.f;
  #pragma unroll
  for (int q = 0; q < 32; ++q){
    int h = wid*32 + q;
    float v = b2f(outp[(size_t)h*NPOS + (size_t)i*NN + j0 + lane]);
    rv[q] = v; s += v; sq += v*v;
  }
  reds[wid][lane] = s; redq[wid][lane] = sq;
  __syncthreads();
  if (tid < 64){
    float ts = reds[0][tid] + reds[1][tid] + reds[2][tid] + reds[3][tid];
    float tq = redq[0][tid] + redq[1][tid] + redq[2][tid] + redq[3][tid];
    float m  = ts * (1.f/128.f);
    float var = tq * (1.f/128.f) - m*m;
    marr[tid] = m; iarr[tid] = rsqrtf(var + EPSV);
  }
  __syncthreads();
  float m = marr[lane], inv = iarr[lane];
  #pragma unroll
  for (int q = 0; q < 32; ++q){
    int h = wid*32 + q;
    float v = (rv[q] - m)*inv*tonw[h] + tonb[h];
    xn2[lane*132 + h] = f2b(v);
  }
  __syncthreads();

  f32x4 acc[8];
  #pragma unroll
  for (int n = 0; n < 8; ++n) acc[n] = {0.f,0.f,0.f,0.f};
  const int row = wid*16 + l15;
  const int kofs = lg * 8;
  #pragma unroll
  for (int ks = 0; ks < 4; ++ks){
    const u16* ap = xn2 + row*132 + ks*32 + kofs;
    bf16x4 a0 = *(const bf16x4*)ap;
    bf16x4 a1 = *(const bf16x4*)(ap + 4);
    bf16x8 af = __builtin_shufflevector(a0, a1, 0,1,2,3,4,5,6,7);
    #pragma unroll
    for (int n = 0; n < 8; ++n){
      bf16x8 bm = *(const bf16x8*)(wOut + (n*16 + l15)*128 + ks*32 + kofs);
      acc[n] = __builtin_amdgcn_mfma_f32_16x16x32_bf16(af, bm, acc[n], 0, 0, 0);
    }
  }
  #pragma unroll
  for (int n = 0; n < 8; ++n){
    int dd = n*16 + l15;
    float bo = out_b[dd];
    #pragma unroll
    for (int r = 0; r < 4; ++r){
      int p = wid*16 + lg*4 + r;
      size_t base = ((size_t)i*NN + j0 + p)*DIMC + dd;
      float g = b2f(gate[base]);
      out[base] = (acc[n][r] + bo) * g;
    }
  }
}

extern "C" void kernel_launch(void* const* d_in, const int* in_sizes, int n_in,
                              void* d_out, int out_size, void* d_ws, size_t ws_size,
                              hipStream_t stream){
  const float* x       = (const float*)d_in[0];
  const float* norm_w  = (const float*)d_in[1];
  const float* norm_b  = (const float*)d_in[2];
  const float* left_w  = (const float*)d_in[3];
  const float* left_b  = (const float*)d_in[4];
  const float* right_w = (const float*)d_in[5];
  const float* right_b = (const float*)d_in[6];
  const float* lgate_w = (const float*)d_in[7];
  const float* lgate_b = (const float*)d_in[8];
  const float* rgate_w = (const float*)d_in[9];
  const float* rgate_b = (const float*)d_in[10];
  const float* ogate_w = (const float*)d_in[11];
  const float* ogate_b = (const float*)d_in[12];
  const float* ton_w   = (const float*)d_in[13];
  const float* ton_b   = (const float*)d_in[14];
  const float* out_w   = (const float*)d_in[15];
  const float* out_b   = (const float*)d_in[16];

  char* ws = (char*)d_ws;
  const size_t SZ = (size_t)NPOS * DIMC * sizeof(u16);
  u16* Lp   = (u16*)(ws);
  u16* Rp   = (u16*)(ws + SZ);
  u16* gate = (u16*)(ws + 2*SZ);
  u16* outp = (u16*)(ws + 3*SZ);
  u16* wb   = (u16*)(ws + 4*SZ);
  u16* xng  = outp;   // xn_g aliases outp: fully consumed by projB before phase2 writes outp

  wconv_k<<<dim3(384), dim3(256), 0, stream>>>(left_w, lgate_w, right_w, rgate_w, ogate_w, out_w, wb);
  ln_k<<<dim3(2304), dim3(256), 0, stream>>>(x, norm_w, norm_b, xng);
  projB_k<<<dim3(5760), dim3(256), 0, stream>>>(xng, wb,
      left_b, lgate_b, right_b, rgate_b, ogate_b, Lp, Rp, gate);
  phase2_k<<<dim3(1152), dim3(256), 0, stream>>>(Rp, Lp, outp);
  phase3_k<<<dim3(2304), dim3(256), 0, stream>>>(outp, ton_w, ton_b, wb + 5*16384, out_b, gate, (float*)d_out);
}